// Round 6
// baseline (162.324 us; speedup 1.0000x reference)
//
#include <hip/hip_runtime.h>
#include <hip/hip_bf16.h>

#define N_SRC   131072
#define N_DST   65536
#define D       128      // D_IN == D_OUT == 128

typedef __bf16 bf16x8 __attribute__((ext_vector_type(8)));
typedef float  f32x4  __attribute__((ext_vector_type(4)));

#define CONV_BLOCKS 8192   // (N_SRC*D) / (256 threads * 8 elems) = 8192
#define W_BLOCKS    64     // 64*256 = 16384 = D*D elements

// ---------------------------------------------------------------------------
// Kernel 1 (fused prep): role-split grid.
//  blocks [0, CONV_BLOCKS)                : feat fp32 -> bf16 (streaming)
//  blocks [CONV_BLOCKS, CONV+n_bnd)       : sorted dst -> CSR row_start
//  blocks [CONV+n_bnd, CONV+n_bnd+64)     : W fp32 [k][n] -> Wt bf16 [n][k]
// ---------------------------------------------------------------------------
__global__ __launch_bounds__(256) void prep_kernel(
    const float* __restrict__ feat,
    const int*   __restrict__ dst, int n_edges, int n_bnd_blocks,
    const float* __restrict__ W_self, const float* __restrict__ W_neigh,
    __bf16* __restrict__ feat_bf,
    int*    __restrict__ row_start,
    __bf16* __restrict__ Wt_self, __bf16* __restrict__ Wt_neigh)
{
    const int b = blockIdx.x;
    const int t = threadIdx.x;

    if (b < CONV_BLOCKS) {
        const size_t i0 = ((size_t)b * 256 + t) * 8;
        const float4 a0 = *(const float4*)&feat[i0];
        const float4 a1 = *(const float4*)&feat[i0 + 4];
        bf16x8 o;
        o[0] = (__bf16)a0.x; o[1] = (__bf16)a0.y; o[2] = (__bf16)a0.z; o[3] = (__bf16)a0.w;
        o[4] = (__bf16)a1.x; o[5] = (__bf16)a1.y; o[6] = (__bf16)a1.z; o[7] = (__bf16)a1.w;
        *(bf16x8*)&feat_bf[i0] = o;
    } else if (b < CONV_BLOCKS + n_bnd_blocks) {
        const int e = (b - CONV_BLOCKS) * 256 + t;
        if (e < n_edges) {
            const int d    = dst[e];
            const int prev = (e == 0) ? -1 : dst[e - 1];
            for (int r = prev + 1; r <= d; ++r) row_start[r] = e;
            if (e == n_edges - 1)
                for (int r = d + 1; r <= N_DST; ++r) row_start[r] = n_edges;
        }
    } else {
        const int wb  = b - CONV_BLOCKS - n_bnd_blocks;  // 0..63
        const int idx = wb * 256 + t;                    // 0..16383
        const int k = idx >> 7, n = idx & 127;
        Wt_self [n * D + k] = (__bf16)W_self [k * D + n];
        Wt_neigh[n * D + k] = (__bf16)W_neigh[k * D + n];
    }
}

// ---------------------------------------------------------------------------
// Kernel 2 (fused neigh + dual GEMM). 512 threads, MTILE=64, grid=1024.
//
// Round-6 change vs round 5 (44.9 us): occupancy was GRID-capped at 2
// blocks/CU (50% max, 32% measured) while VGPR=52 and LDS=33KB allowed 4.
// MTILE 128->64 doubles the grid: 4 blocks/CU = 2048 thr/CU = full 32-wave
// ceiling. Per-group serial row chain halves (2 rows vs 4); wave-lockstep
// divergence waste (E[max over groups of ceil(deg/8)]) shrinks with it.
// UNLIKE r2's failed MTILE=64: gather code and register budget identical to
// r5 (no launch-bounds squeeze), and MREP=2 B-reuse is preserved by the new
// 2 row-halves x 4 col-quarters wave partition (total weight traffic
// unchanged vs r5: 8 B-frag loads/wave/path, 2x fewer MFMAs/wave).
//
// Phase 1: gather-mean, 32 groups x 16 lanes, group owns 2 rows; predicated
//   unroll-8, mask-FMA, pipelined idx prefetch; LDS store XOR-swizzle
//   byte^=(row&7)<<4 (conflict-free ds_read_b128; verified r1-r5).
// Phase 2: self-GEMM from global (before barrier, absorbs gather
//   imbalance), barrier, neigh-GEMM from swizzled LDS.
//   MFMA bf16 16x16x32 layouts (HW-verified):
//     A: lane holds A[m = lane&15][k = (lane>>4)*8 + j]
//     B: lane holds B[k = (lane>>4)*8 + j][n = lane&15]   (from Wt[n][k])
//     C/D: col = lane&15, row = (lane>>4)*4 + reg
// ---------------------------------------------------------------------------
#define MTILE 64
#define MREP  2
#define NBLK  2      // nb-blocks per wave (col-quarter = 32 cols)

__global__ __launch_bounds__(512) void fused_kernel(
    const __bf16* __restrict__ feat_bf,   // bf16 N_SRC x D
    const int*    __restrict__ src,
    const int*    __restrict__ row_start,
    const __bf16* __restrict__ Wt_self,   // bf16 [n][k]
    const __bf16* __restrict__ Wt_neigh,  // bf16 [n][k]
    const float*  __restrict__ b_self,
    const float*  __restrict__ b_neigh,
    float*        __restrict__ out)
{
    __shared__ __align__(16) __bf16 hs[MTILE * D];   // 16 KB, XOR-swizzled rows
    __shared__ int rs[MTILE + 1];
    char* hsb = (char*)hs;

    const int t     = threadIdx.x;
    const int tile0 = blockIdx.x * MTILE;

    // stage CSR bounds for this tile (1 coalesced load, kills per-row trips)
    if (t <= MTILE) rs[t] = row_start[tile0 + t];
    __syncthreads();

    // ---------------- phase 1: gather-mean into LDS ----------------
    {
        const int g    = t >> 4;       // group 0..31
        const int lane = t & 15;
        const int cb   = lane * 16;    // byte offset of this lane's 16B chunk

        #pragma unroll
        for (int rr = 0; rr < MTILE / 32; ++rr) {   // 2 rows per group
            const int rloc = rr * 32 + g;
            const int s0 = rs[rloc];
            const int s1 = rs[rloc + 1];

            float acc[8] = {0.f, 0.f, 0.f, 0.f, 0.f, 0.f, 0.f, 0.f};

            // prefetch first index batch (clamped; idx loads are sequential
            // L1/L2-hot, cheap -- feature gathers below are never padded)
            int idx[8];
            #pragma unroll
            for (int j = 0; j < 8; ++j) {
                int e = s0 + j; e = e < s1 ? e : s1 - 1; e = e > 0 ? e : 0;
                idx[j] = src[e];
            }

            for (int base = s0; base < s1; base += 8) {
                bf16x8 v[8];
                #pragma unroll
                for (int j = 0; j < 8; ++j)
                    v[j] = *(const bf16x8*)((const char*)feat_bf + (size_t)idx[j] * (D * 2) + cb);
                // prefetch next index batch under the gather latency
                int nidx[8];
                #pragma unroll
                for (int j = 0; j < 8; ++j) {
                    int e = base + 8 + j; e = e < s1 ? e : s1 - 1; e = e > 0 ? e : 0;
                    nidx[j] = src[e];
                }
                #pragma unroll
                for (int j = 0; j < 8; ++j) {
                    const float m = (base + j < s1) ? 1.0f : 0.0f;
                    #pragma unroll
                    for (int c = 0; c < 8; ++c)
                        acc[c] = fmaf(m, (float)v[j][c], acc[c]);
                }
                #pragma unroll
                for (int j = 0; j < 8; ++j) idx[j] = nidx[j];
            }

            const float inv = 1.0f / fmaxf((float)(s1 - s0), 1.0f);
            bf16x8 o;
            #pragma unroll
            for (int c = 0; c < 8; ++c) o[c] = (__bf16)(acc[c] * inv);
            // swizzled LDS store (row stride 256 B, chunk XOR by row&7)
            *(bf16x8*)(hsb + rloc * 256 + (cb ^ ((rloc & 7) << 4))) = o;
        }
    }

    // ---------------- phase 2: dual GEMM (8 waves, 2 rows x 4 col-qtrs) ----
    const int w     = t >> 6;         // wave 0..7
    const int l     = t & 63;
    const int m16   = l & 15;
    const int quad  = l >> 4;         // 0..3
    const int kb    = quad * 8;
    const int wrow  = w & 1;          // row half (0: rows 0-31, 1: 32-63)
    const int wcol  = w >> 1;         // col quarter (32 cols each)
    const int rowloc0 = wrow * (16 * MREP);
    const int rowbase = tile0 + rowloc0;
    const int colbase = wcol * (16 * NBLK);

    f32x4 acc[MREP][NBLK];
    #pragma unroll
    for (int rp = 0; rp < MREP; ++rp)
        #pragma unroll
        for (int nb = 0; nb < NBLK; ++nb)
            acc[rp][nb] = (f32x4){0.f, 0.f, 0.f, 0.f};

    // self path: A straight from global bf16 (no LDS dep -> before barrier)
    #pragma unroll
    for (int ks = 0; ks < 4; ++ks) {
        bf16x8 afrag[MREP];
        #pragma unroll
        for (int rp = 0; rp < MREP; ++rp)
            afrag[rp] = *(const bf16x8*)&feat_bf[(size_t)(rowbase + rp * 16 + m16) * D + ks * 32 + kb];
        #pragma unroll
        for (int nb = 0; nb < NBLK; ++nb) {
            const bf16x8 bfrag = *(const bf16x8*)&Wt_self[(size_t)(colbase + nb * 16 + m16) * D + ks * 32 + kb];
            #pragma unroll
            for (int rp = 0; rp < MREP; ++rp)
                acc[rp][nb] = __builtin_amdgcn_mfma_f32_16x16x32_bf16(
                    afrag[rp], bfrag, acc[rp][nb], 0, 0, 0);
        }
    }

    __syncthreads();

    // neigh path: A from swizzled LDS tile
    #pragma unroll
    for (int ks = 0; ks < 4; ++ks) {
        bf16x8 afrag[MREP];
        #pragma unroll
        for (int rp = 0; rp < MREP; ++rp) {
            const int rloc  = rowloc0 + rp * 16 + m16;
            const int cbyte = (ks * 32 + kb) * 2;
            afrag[rp] = *(const bf16x8*)(hsb + rloc * 256 + (cbyte ^ ((rloc & 7) << 4)));
        }
        #pragma unroll
        for (int nb = 0; nb < NBLK; ++nb) {
            const bf16x8 bfrag = *(const bf16x8*)&Wt_neigh[(size_t)(colbase + nb * 16 + m16) * D + ks * 32 + kb];
            #pragma unroll
            for (int rp = 0; rp < MREP; ++rp)
                acc[rp][nb] = __builtin_amdgcn_mfma_f32_16x16x32_bf16(
                    afrag[rp], bfrag, acc[rp][nb], 0, 0, 0);
        }
    }

    // epilogue
    #pragma unroll
    for (int nb = 0; nb < NBLK; ++nb) {
        const int col  = colbase + nb * 16 + m16;
        const float bias = b_self[col] + b_neigh[col];
        #pragma unroll
        for (int rp = 0; rp < MREP; ++rp) {
            const int orow0 = rowbase + rp * 16 + quad * 4;
            #pragma unroll
            for (int r = 0; r < 4; ++r)
                out[(size_t)(orow0 + r) * D + col] = acc[rp][nb][r] + bias;
        }
    }
}

// ---------------------------------------------------------------------------
extern "C" void kernel_launch(void* const* d_in, const int* in_sizes, int n_in,
                              void* d_out, int out_size, void* d_ws, size_t ws_size,
                              hipStream_t stream)
{
    const float* feat    = (const float*)d_in[0];
    const float* W_self  = (const float*)d_in[1];
    const float* b_self  = (const float*)d_in[2];
    const float* W_neigh = (const float*)d_in[3];
    const float* b_neigh = (const float*)d_in[4];
    const int*   src_idx = (const int*)d_in[5];
    const int*   dst_idx = (const int*)d_in[6];
    const int n_edges = in_sizes[5];

    // workspace layout
    char* ws = (char*)d_ws;
    __bf16* feat_bf  = (__bf16*)ws;                                  // 32 MB
    int*    row_start = (int*)(feat_bf + (size_t)N_SRC * D);         // 256 KB
    __bf16* Wt_self  = (__bf16*)(row_start + N_DST + 16);
    __bf16* Wt_neigh = Wt_self + D * D;

    const int n_bnd = (n_edges + 255) / 256;
    prep_kernel<<<CONV_BLOCKS + n_bnd + W_BLOCKS, 256, 0, stream>>>(
        feat, dst_idx, n_edges, n_bnd, W_self, W_neigh,
        feat_bf, row_start, Wt_self, Wt_neigh);

    fused_kernel<<<N_DST / MTILE, 512, 0, stream>>>(
        feat_bf, src_idx, row_start, Wt_self, Wt_neigh,
        b_self, b_neigh, (float*)d_out);
}

// Round 7
// 157.186 us; speedup vs baseline: 1.0327x; 1.0327x over previous
//
#include <hip/hip_runtime.h>
#include <hip/hip_bf16.h>

#define N_SRC   131072
#define N_DST   65536
#define D       128      // D_IN == D_OUT == 128

typedef __bf16 bf16x8 __attribute__((ext_vector_type(8)));
typedef float  f32x4  __attribute__((ext_vector_type(4)));

#define W_BLOCKS 64     // 64*256 = 16384 = D*D elements

// ---------------------------------------------------------------------------
// Kernel 1 (prep, round-7: SMALL): CSR bounds + W transpose only.
// The feat fp32->bf16 conversion pass (96 MB of streaming, ~15 us) is GONE:
// rocprof r5/r6 showed the gather phase has large slack in every pipe
// (VALU 24%, HBM 36% of achievable, >10x latency-BW headroom), so the fused
// kernel gathers fp32 directly and the bandwidth "savings" of bf16 staging
// never paid for its cost.
//  blocks [0, n_bnd)        : sorted dst -> CSR row_start
//  blocks [n_bnd, n_bnd+64) : W fp32 [k][n] -> Wt bf16 [n][k]
// ---------------------------------------------------------------------------
__global__ __launch_bounds__(256) void prep_kernel(
    const int*   __restrict__ dst, int n_edges, int n_bnd_blocks,
    const float* __restrict__ W_self, const float* __restrict__ W_neigh,
    int*    __restrict__ row_start,
    __bf16* __restrict__ Wt_self, __bf16* __restrict__ Wt_neigh)
{
    const int b = blockIdx.x;
    const int t = threadIdx.x;

    if (b < n_bnd_blocks) {
        const int e = b * 256 + t;
        if (e < n_edges) {
            const int d    = dst[e];
            const int prev = (e == 0) ? -1 : dst[e - 1];
            for (int r = prev + 1; r <= d; ++r) row_start[r] = e;
            if (e == n_edges - 1)
                for (int r = d + 1; r <= N_DST; ++r) row_start[r] = n_edges;
        }
    } else {
        const int wb  = b - n_bnd_blocks;                // 0..63
        const int idx = wb * 256 + t;                    // 0..16383
        const int k = idx >> 7, n = idx & 127;
        Wt_self [n * D + k] = (__bf16)W_self [k * D + n];
        Wt_neigh[n * D + k] = (__bf16)W_neigh[k * D + n];
    }
}

// ---------------------------------------------------------------------------
// Kernel 2 (fused neigh + dual GEMM). 512 threads, MTILE=128, grid=512 --
// r5's proven structure (44.9 us, best of r1-r6; every tile-shrink or
// wave-repartition attempt regressed).
//
// Round-7 change: gather reads fp32 feat directly (512 B/row, two float4
// per lane instead of one bf16x8). 16 independent 16 B loads in flight per
// lane (2x the MLP of r5), fp32 accumulate (accuracy up). Self-path GEMM
// A-fragments also load fp32 and convert to bf16 in-register (8 v_cvt per
// fragment). Everything downstream (LDS tile, swizzle, MFMA shape,
// col-split wave partition) is byte-identical to r5.
//
// Phase 1: gather-mean, 32 groups x 16 lanes, group owns 4 rows; predicated
//   unroll-8, mask-FMA, pipelined idx prefetch; LDS store XOR-swizzle
//   byte^=(row&7)<<4 (conflict-free ds_read_b128; verified r1-r6).
// Phase 2: self-GEMM from global fp32 (before barrier, absorbs gather
//   imbalance), barrier, neigh-GEMM from swizzled LDS.
//   MFMA bf16 16x16x32 layouts (HW-verified):
//     A: lane holds A[m = lane&15][k = (lane>>4)*8 + j]
//     B: lane holds B[k = (lane>>4)*8 + j][n = lane&15]   (from Wt[n][k])
//     C/D: col = lane&15, row = (lane>>4)*4 + reg
// ---------------------------------------------------------------------------
#define MTILE 128
#define MREP  2
#define NBLK  4      // nb-blocks per wave (col half = 64 cols), r5 partition

__global__ __launch_bounds__(512) void fused_kernel(
    const float* __restrict__ feat,       // fp32 N_SRC x D
    const int*   __restrict__ src,
    const int*   __restrict__ row_start,
    const __bf16* __restrict__ Wt_self,   // bf16 [n][k]
    const __bf16* __restrict__ Wt_neigh,  // bf16 [n][k]
    const float*  __restrict__ b_self,
    const float*  __restrict__ b_neigh,
    float*        __restrict__ out)
{
    __shared__ __align__(16) __bf16 hs[MTILE * D];   // 32 KB, XOR-swizzled rows
    __shared__ int rs[MTILE + 1];
    char* hsb = (char*)hs;

    const int t     = threadIdx.x;
    const int tile0 = blockIdx.x * MTILE;

    // stage CSR bounds for this tile (1 coalesced load, kills per-row trips)
    if (t <= MTILE) rs[t] = row_start[tile0 + t];
    __syncthreads();

    // ---------------- phase 1: gather-mean (fp32) into LDS ----------------
    {
        const int g    = t >> 4;       // group 0..31
        const int lane = t & 15;
        const int c0   = lane * 8;     // first of this lane's 8 fp32 cols
        const int cb   = lane * 16;    // byte offset of lane's 16B bf16 chunk

        #pragma unroll
        for (int rr = 0; rr < MTILE / 32; ++rr) {   // 4 rows per group
            const int rloc = rr * 32 + g;
            const int s0 = rs[rloc];
            const int s1 = rs[rloc + 1];

            float acc[8] = {0.f, 0.f, 0.f, 0.f, 0.f, 0.f, 0.f, 0.f};

            // prefetch first index batch (clamped; idx loads are sequential
            // L1/L2-hot, cheap -- feature gathers below are never padded)
            int idx[8];
            #pragma unroll
            for (int j = 0; j < 8; ++j) {
                int e = s0 + j; e = e < s1 ? e : s1 - 1; e = e > 0 ? e : 0;
                idx[j] = src[e];
            }

            for (int base = s0; base < s1; base += 8) {
                // 16 independent 16B loads in flight (2 float4 per edge)
                f32x4 va[8], vb[8];
                #pragma unroll
                for (int j = 0; j < 8; ++j) {
                    const float* p = feat + (size_t)idx[j] * D + c0;
                    va[j] = *(const f32x4*)p;
                    vb[j] = *(const f32x4*)(p + 4);
                }
                // prefetch next index batch under the gather latency
                int nidx[8];
                #pragma unroll
                for (int j = 0; j < 8; ++j) {
                    int e = base + 8 + j; e = e < s1 ? e : s1 - 1; e = e > 0 ? e : 0;
                    nidx[j] = src[e];
                }
                #pragma unroll
                for (int j = 0; j < 8; ++j) {
                    const float m = (base + j < s1) ? 1.0f : 0.0f;
                    #pragma unroll
                    for (int c = 0; c < 4; ++c)
                        acc[c] = fmaf(m, va[j][c], acc[c]);
                    #pragma unroll
                    for (int c = 0; c < 4; ++c)
                        acc[4 + c] = fmaf(m, vb[j][c], acc[4 + c]);
                }
                #pragma unroll
                for (int j = 0; j < 8; ++j) idx[j] = nidx[j];
            }

            const float inv = 1.0f / fmaxf((float)(s1 - s0), 1.0f);
            bf16x8 o;
            #pragma unroll
            for (int c = 0; c < 8; ++c) o[c] = (__bf16)(acc[c] * inv);
            // swizzled LDS store (row stride 256 B, chunk XOR by row&7)
            *(bf16x8*)(hsb + rloc * 256 + (cb ^ ((rloc & 7) << 4))) = o;
        }
    }

    // ---------------- phase 2: dual GEMM (all 8 waves, col-split) ----------
    const int w     = t >> 6;         // wave 0..7
    const int l     = t & 63;
    const int m16   = l & 15;
    const int quad  = l >> 4;         // 0..3
    const int kb    = quad * 8;
    const int wrow  = w & 3;          // row-quarter of the tile
    const int whalf = w >> 2;         // column half (0: cols 0-63, 1: 64-127)
    const int rowloc0 = wrow * (16 * MREP);
    const int rowbase = tile0 + rowloc0;
    const int colbase = whalf * 64;

    f32x4 acc[MREP][NBLK];
    #pragma unroll
    for (int rp = 0; rp < MREP; ++rp)
        #pragma unroll
        for (int nb = 0; nb < NBLK; ++nb)
            acc[rp][nb] = (f32x4){0.f, 0.f, 0.f, 0.f};

    // self path: A from global fp32, converted in-reg (no LDS dep ->
    // before barrier, absorbs gather imbalance)
    #pragma unroll
    for (int ks = 0; ks < 4; ++ks) {
        bf16x8 afrag[MREP];
        #pragma unroll
        for (int rp = 0; rp < MREP; ++rp) {
            const float* ap = &feat[(size_t)(rowbase + rp * 16 + m16) * D + ks * 32 + kb];
            const f32x4 x0 = *(const f32x4*)ap;
            const f32x4 x1 = *(const f32x4*)(ap + 4);
            #pragma unroll
            for (int c = 0; c < 4; ++c) afrag[rp][c]     = (__bf16)x0[c];
            #pragma unroll
            for (int c = 0; c < 4; ++c) afrag[rp][4 + c] = (__bf16)x1[c];
        }
        #pragma unroll
        for (int nb = 0; nb < NBLK; ++nb) {
            const bf16x8 bfrag = *(const bf16x8*)&Wt_self[(size_t)(colbase + nb * 16 + m16) * D + ks * 32 + kb];
            #pragma unroll
            for (int rp = 0; rp < MREP; ++rp)
                acc[rp][nb] = __builtin_amdgcn_mfma_f32_16x16x32_bf16(
                    afrag[rp], bfrag, acc[rp][nb], 0, 0, 0);
        }
    }

    __syncthreads();

    // neigh path: A from swizzled LDS tile
    #pragma unroll
    for (int ks = 0; ks < 4; ++ks) {
        bf16x8 afrag[MREP];
        #pragma unroll
        for (int rp = 0; rp < MREP; ++rp) {
            const int rloc  = rowloc0 + rp * 16 + m16;
            const int cbyte = (ks * 32 + kb) * 2;
            afrag[rp] = *(const bf16x8*)(hsb + rloc * 256 + (cbyte ^ ((rloc & 7) << 4)));
        }
        #pragma unroll
        for (int nb = 0; nb < NBLK; ++nb) {
            const bf16x8 bfrag = *(const bf16x8*)&Wt_neigh[(size_t)(colbase + nb * 16 + m16) * D + ks * 32 + kb];
            #pragma unroll
            for (int rp = 0; rp < MREP; ++rp)
                acc[rp][nb] = __builtin_amdgcn_mfma_f32_16x16x32_bf16(
                    afrag[rp], bfrag, acc[rp][nb], 0, 0, 0);
        }
    }

    // epilogue
    #pragma unroll
    for (int nb = 0; nb < NBLK; ++nb) {
        const int col  = colbase + nb * 16 + m16;
        const float bias = b_self[col] + b_neigh[col];
        #pragma unroll
        for (int rp = 0; rp < MREP; ++rp) {
            const int orow0 = rowbase + rp * 16 + quad * 4;
            #pragma unroll
            for (int r = 0; r < 4; ++r)
                out[(size_t)(orow0 + r) * D + col] = acc[rp][nb][r] + bias;
        }
    }
}

// ---------------------------------------------------------------------------
extern "C" void kernel_launch(void* const* d_in, const int* in_sizes, int n_in,
                              void* d_out, int out_size, void* d_ws, size_t ws_size,
                              hipStream_t stream)
{
    const float* feat    = (const float*)d_in[0];
    const float* W_self  = (const float*)d_in[1];
    const float* b_self  = (const float*)d_in[2];
    const float* W_neigh = (const float*)d_in[3];
    const float* b_neigh = (const float*)d_in[4];
    const int*   src_idx = (const int*)d_in[5];
    const int*   dst_idx = (const int*)d_in[6];
    const int n_edges = in_sizes[5];

    // workspace layout (feat_bf staging buffer eliminated this round)
    char* ws = (char*)d_ws;
    int*    row_start = (int*)ws;                                    // 256 KB
    __bf16* Wt_self   = (__bf16*)(row_start + N_DST + 16);
    __bf16* Wt_neigh  = Wt_self + D * D;

    const int n_bnd = (n_edges + 255) / 256;
    prep_kernel<<<n_bnd + W_BLOCKS, 256, 0, stream>>>(
        dst_idx, n_edges, n_bnd, W_self, W_neigh,
        row_start, Wt_self, Wt_neigh);

    fused_kernel<<<N_DST / MTILE, 512, 0, stream>>>(
        feat, src_idx, row_start, Wt_self, Wt_neigh,
        b_self, b_neigh, (float*)d_out);
}

// Round 8
// 155.787 us; speedup vs baseline: 1.0420x; 1.0090x over previous
//
#include <hip/hip_runtime.h>
#include <hip/hip_bf16.h>

#define N_SRC   131072
#define N_DST   65536
#define D       128      // D_IN == D_OUT == 128

typedef __bf16 bf16x8 __attribute__((ext_vector_type(8)));
typedef float  f32x4  __attribute__((ext_vector_type(4)));

#define CONV_BLOCKS 8192   // (N_SRC*D) / (256 threads * 8 elems) = 8192
#define W_BLOCKS    64     // 64*256 = 16384 = D*D elements

// ---------------------------------------------------------------------------
// FINAL (round 8 = revert to round-5 best, 155.3 us measured).
//
// Why this configuration is the ceiling (byte-time accounting, r5 vs r7):
//   r5: prep 96 MB streaming + fused 103 MB  -> 60 us  -> 3.3 TB/s
//   r7: prep  ~2 MB          + fused 191 MB  -> 64 us  -> 3.0 TB/s
// Two different byte decompositions, same total time: the pipeline is
// pinned at ~3.3 TB/s effective for this traffic mix (random 256 B
// gather granules run at ~half the 6.3 TB/s streaming ceiling). Compulsory
// traffic ~200 MB -> ~60 us kernel-side floor; plus the fixed harness
// fills (~81 us) + launch gaps -> ~155 us total. Tile-shrink (r2,r6),
// wave-repartition (r4), MLP-doubling (r7) all regressed or were neutral.
//
// Kernel 1 (fused prep): role-split grid.
//  blocks [0, CONV_BLOCKS)                : feat fp32 -> bf16 (streaming)
//  blocks [CONV_BLOCKS, CONV+n_bnd)       : sorted dst -> CSR row_start
//  blocks [CONV+n_bnd, CONV+n_bnd+64)     : W fp32 [k][n] -> Wt bf16 [n][k]
// ---------------------------------------------------------------------------
__global__ __launch_bounds__(256) void prep_kernel(
    const float* __restrict__ feat,
    const int*   __restrict__ dst, int n_edges, int n_bnd_blocks,
    const float* __restrict__ W_self, const float* __restrict__ W_neigh,
    __bf16* __restrict__ feat_bf,
    int*    __restrict__ row_start,
    __bf16* __restrict__ Wt_self, __bf16* __restrict__ Wt_neigh)
{
    const int b = blockIdx.x;
    const int t = threadIdx.x;

    if (b < CONV_BLOCKS) {
        const size_t i0 = ((size_t)b * 256 + t) * 8;
        const float4 a0 = *(const float4*)&feat[i0];
        const float4 a1 = *(const float4*)&feat[i0 + 4];
        bf16x8 o;
        o[0] = (__bf16)a0.x; o[1] = (__bf16)a0.y; o[2] = (__bf16)a0.z; o[3] = (__bf16)a0.w;
        o[4] = (__bf16)a1.x; o[5] = (__bf16)a1.y; o[6] = (__bf16)a1.z; o[7] = (__bf16)a1.w;
        *(bf16x8*)&feat_bf[i0] = o;
    } else if (b < CONV_BLOCKS + n_bnd_blocks) {
        const int e = (b - CONV_BLOCKS) * 256 + t;
        if (e < n_edges) {
            const int d    = dst[e];
            const int prev = (e == 0) ? -1 : dst[e - 1];
            for (int r = prev + 1; r <= d; ++r) row_start[r] = e;
            if (e == n_edges - 1)
                for (int r = d + 1; r <= N_DST; ++r) row_start[r] = n_edges;
        }
    } else {
        const int wb  = b - CONV_BLOCKS - n_bnd_blocks;  // 0..63
        const int idx = wb * 256 + t;                    // 0..16383
        const int k = idx >> 7, n = idx & 127;
        Wt_self [n * D + k] = (__bf16)W_self [k * D + n];
        Wt_neigh[n * D + k] = (__bf16)W_neigh[k * D + n];
    }
}

// ---------------------------------------------------------------------------
// Kernel 2 (fused neigh + dual GEMM). 512 threads, MTILE=128, grid=512.
// Measured best (r5): fused 44.9 us, VGPR=52, occupancy 32%, bank-conflict ~0.
//
// Phase 1: gather-mean, 32 groups x 16 lanes, group owns 4 rows; predicated
//   unroll-8, mask-FMA, pipelined idx prefetch; LDS store XOR-swizzle
//   byte^=(row&7)<<4 (conflict-free ds_read_b128; verified r1-r6).
// Phase 2: col-split dual GEMM across all 8 waves: wave w owns rows
//   (w&3)*32..+31 (MREP=2, B-frag reuse x2) and cols (w>>2)*64..+63.
//   Self-GEMM from global before the barrier (absorbs gather imbalance),
//   then neigh-GEMM from the swizzled LDS tile.
//   MFMA bf16 16x16x32 layouts (HW-verified):
//     A: lane holds A[m = lane&15][k = (lane>>4)*8 + j]
//     B: lane holds B[k = (lane>>4)*8 + j][n = lane&15]   (from Wt[n][k])
//     C/D: col = lane&15, row = (lane>>4)*4 + reg
// ---------------------------------------------------------------------------
#define MTILE 128
#define MREP  2

__global__ __launch_bounds__(512) void fused_kernel(
    const __bf16* __restrict__ feat_bf,   // bf16 N_SRC x D
    const int*    __restrict__ src,
    const int*    __restrict__ row_start,
    const __bf16* __restrict__ Wt_self,   // bf16 [n][k]
    const __bf16* __restrict__ Wt_neigh,  // bf16 [n][k]
    const float*  __restrict__ b_self,
    const float*  __restrict__ b_neigh,
    float*        __restrict__ out)
{
    __shared__ __align__(16) __bf16 hs[MTILE * D];   // 32 KB, XOR-swizzled rows
    __shared__ int rs[MTILE + 1];
    char* hsb = (char*)hs;

    const int t     = threadIdx.x;
    const int tile0 = blockIdx.x * MTILE;

    // stage CSR bounds for this tile (1 coalesced load, kills per-row trips)
    if (t <= MTILE) rs[t] = row_start[tile0 + t];
    __syncthreads();

    // ---------------- phase 1: gather-mean into LDS ----------------
    {
        const int g    = t >> 4;       // group 0..31
        const int lane = t & 15;
        const int cb   = lane * 16;    // byte offset of this lane's 16B chunk

        #pragma unroll
        for (int rr = 0; rr < MTILE / 32; ++rr) {   // 4 rows per group
            const int rloc = rr * 32 + g;
            const int s0 = rs[rloc];
            const int s1 = rs[rloc + 1];

            float acc[8] = {0.f, 0.f, 0.f, 0.f, 0.f, 0.f, 0.f, 0.f};

            // prefetch first index batch (clamped; idx loads are sequential
            // L1/L2-hot, cheap -- feature gathers below are never padded)
            int idx[8];
            #pragma unroll
            for (int j = 0; j < 8; ++j) {
                int e = s0 + j; e = e < s1 ? e : s1 - 1; e = e > 0 ? e : 0;
                idx[j] = src[e];
            }

            for (int base = s0; base < s1; base += 8) {
                bf16x8 v[8];
                #pragma unroll
                for (int j = 0; j < 8; ++j)
                    v[j] = *(const bf16x8*)((const char*)feat_bf + (size_t)idx[j] * (D * 2) + cb);
                // prefetch next index batch under the gather latency
                int nidx[8];
                #pragma unroll
                for (int j = 0; j < 8; ++j) {
                    int e = base + 8 + j; e = e < s1 ? e : s1 - 1; e = e > 0 ? e : 0;
                    nidx[j] = src[e];
                }
                #pragma unroll
                for (int j = 0; j < 8; ++j) {
                    const float m = (base + j < s1) ? 1.0f : 0.0f;
                    #pragma unroll
                    for (int c = 0; c < 8; ++c)
                        acc[c] = fmaf(m, (float)v[j][c], acc[c]);
                }
                #pragma unroll
                for (int j = 0; j < 8; ++j) idx[j] = nidx[j];
            }

            const float inv = 1.0f / fmaxf((float)(s1 - s0), 1.0f);
            bf16x8 o;
            #pragma unroll
            for (int c = 0; c < 8; ++c) o[c] = (__bf16)(acc[c] * inv);
            // swizzled LDS store (row stride 256 B, chunk XOR by row&7)
            *(bf16x8*)(hsb + rloc * 256 + (cb ^ ((rloc & 7) << 4))) = o;
        }
    }

    // ---------------- phase 2: dual GEMM (all 8 waves, col-split) ----------
    const int w     = t >> 6;         // wave 0..7
    const int l     = t & 63;
    const int m16   = l & 15;
    const int quad  = l >> 4;         // 0..3
    const int kb    = quad * 8;
    const int wrow  = w & 3;          // row-quarter of the tile
    const int whalf = w >> 2;         // column half (0: cols 0-63, 1: 64-127)
    const int rowloc0 = wrow * (16 * MREP);
    const int rowbase = tile0 + rowloc0;
    const int colbase = whalf * 64;

    f32x4 acc[MREP][4];
    #pragma unroll
    for (int rp = 0; rp < MREP; ++rp)
        #pragma unroll
        for (int nb = 0; nb < 4; ++nb)
            acc[rp][nb] = (f32x4){0.f, 0.f, 0.f, 0.f};

    // self path: A straight from global bf16 (no LDS dep -> before barrier)
    #pragma unroll
    for (int ks = 0; ks < 4; ++ks) {
        bf16x8 afrag[MREP];
        #pragma unroll
        for (int rp = 0; rp < MREP; ++rp)
            afrag[rp] = *(const bf16x8*)&feat_bf[(size_t)(rowbase + rp * 16 + m16) * D + ks * 32 + kb];
        #pragma unroll
        for (int nb = 0; nb < 4; ++nb) {
            const bf16x8 bfrag = *(const bf16x8*)&Wt_self[(size_t)(colbase + nb * 16 + m16) * D + ks * 32 + kb];
            #pragma unroll
            for (int rp = 0; rp < MREP; ++rp)
                acc[rp][nb] = __builtin_amdgcn_mfma_f32_16x16x32_bf16(
                    afrag[rp], bfrag, acc[rp][nb], 0, 0, 0);
        }
    }

    __syncthreads();

    // neigh path: A from swizzled LDS tile
    #pragma unroll
    for (int ks = 0; ks < 4; ++ks) {
        bf16x8 afrag[MREP];
        #pragma unroll
        for (int rp = 0; rp < MREP; ++rp) {
            const int rloc  = rowloc0 + rp * 16 + m16;
            const int cbyte = (ks * 32 + kb) * 2;
            afrag[rp] = *(const bf16x8*)(hsb + rloc * 256 + (cbyte ^ ((rloc & 7) << 4)));
        }
        #pragma unroll
        for (int nb = 0; nb < 4; ++nb) {
            const bf16x8 bfrag = *(const bf16x8*)&Wt_neigh[(size_t)(colbase + nb * 16 + m16) * D + ks * 32 + kb];
            #pragma unroll
            for (int rp = 0; rp < MREP; ++rp)
                acc[rp][nb] = __builtin_amdgcn_mfma_f32_16x16x32_bf16(
                    afrag[rp], bfrag, acc[rp][nb], 0, 0, 0);
        }
    }

    // epilogue
    #pragma unroll
    for (int nb = 0; nb < 4; ++nb) {
        const int col  = colbase + nb * 16 + m16;
        const float bias = b_self[col] + b_neigh[col];
        #pragma unroll
        for (int rp = 0; rp < MREP; ++rp) {
            const int orow0 = rowbase + rp * 16 + quad * 4;
            #pragma unroll
            for (int r = 0; r < 4; ++r)
                out[(size_t)(orow0 + r) * D + col] = acc[rp][nb][r] + bias;
        }
    }
}

// ---------------------------------------------------------------------------
extern "C" void kernel_launch(void* const* d_in, const int* in_sizes, int n_in,
                              void* d_out, int out_size, void* d_ws, size_t ws_size,
                              hipStream_t stream)
{
    const float* feat    = (const float*)d_in[0];
    const float* W_self  = (const float*)d_in[1];
    const float* b_self  = (const float*)d_in[2];
    const float* W_neigh = (const float*)d_in[3];
    const float* b_neigh = (const float*)d_in[4];
    const int*   src_idx = (const int*)d_in[5];
    const int*   dst_idx = (const int*)d_in[6];
    const int n_edges = in_sizes[5];

    // workspace layout
    char* ws = (char*)d_ws;
    __bf16* feat_bf  = (__bf16*)ws;                                  // 32 MB
    int*    row_start = (int*)(feat_bf + (size_t)N_SRC * D);         // 256 KB
    __bf16* Wt_self  = (__bf16*)(row_start + N_DST + 16);
    __bf16* Wt_neigh = Wt_self + D * D;

    const int n_bnd = (n_edges + 255) / 256;
    prep_kernel<<<CONV_BLOCKS + n_bnd + W_BLOCKS, 256, 0, stream>>>(
        feat, dst_idx, n_edges, n_bnd, W_self, W_neigh,
        feat_bf, row_start, Wt_self, Wt_neigh);

    fused_kernel<<<N_DST / MTILE, 512, 0, stream>>>(
        feat_bf, src_idx, row_start, Wt_self, Wt_neigh,
        b_self, b_neigh, (float*)d_out);
}